// Round 11
// baseline (1185.472 us; speedup 1.0000x reference)
//
#include <hip/hip_runtime.h>
#include <math.h>

// Hungarian (reference-exact degenerate JV) + MSE.
// Anchored on the round-10 bit-exact kernel (1141us). Changes vs r10:
//   * scan-mask elimination: shadow scan-dual sv[k] (= v[k] when free,
//     -inf when marked). m[k] = ((double)c - ui0) - sv[k] with NO masking ops:
//     free columns -> bit-identical value/instructions; marked -> +inf
//     (finite - -inf), the same sentinel as before, NaN-free. sv restored
//     (sv[k] = v[k]) once per row after augment.
//   * packed 16B {u,cx,cy} split back into uofc[] (double, 8B stride: 2-way
//     bank aliasing = free) + cofc[] (float2): r10's RMW was 8-way conflicted
//     (SQ_LDS_BANK_CONFLICT 43k). Hop = 3 parallel uniform reads.
// HARD RULE (r2/r3/r9): cross-lane MUTABLE state (pcol, uofc, cofc) lives in
// LDS with live reads; readlane only for read-only data or same-step temps.

#define N 256

static __device__ __forceinline__ int f2i(float x) { union { float f; int i; } u; u.f = x; return u.i; }
static __device__ __forceinline__ float i2f(int x) { union { float f; int i; } u; u.i = x; return u.f; }
static __device__ __forceinline__ double mkd(int lo, int hi) {
  union { unsigned long long u; double d; } w;
  w.u = (((unsigned long long)(unsigned)hi) << 32) | (unsigned)lo;
  return w.d;
}
static __device__ __forceinline__ int dlo(double d) { union { double d; unsigned long long u; } w; w.d = d; return (int)(unsigned)w.u; }
static __device__ __forceinline__ int dhi(double d) { union { double d; unsigned long long u; } w; w.d = d; return (int)(unsigned)(w.u >> 32); }

// One DPP f64-min stage with LITERAL ctrl/row_mask. Masked-out lanes keep
// their own bm (old operand). fmin == strict-< select for NaN-free values.
#define DPP_MIN_STAGE(CTRL, RMASK)                                              \
  {                                                                             \
    int mlo = dlo(bm), mhi = dhi(bm);                                           \
    int slo = __builtin_amdgcn_update_dpp(mlo, mlo, CTRL, RMASK, 0xF, false);   \
    int shi = __builtin_amdgcn_update_dpp(mhi, mhi, CTRL, RMASK, 0xF, false);   \
    bm = fmin(bm, mkd(slo, shi));                                               \
  }

__global__ __launch_bounds__(64) void hung_kernel(const float* __restrict__ pred,
                                                  const float* __restrict__ target,
                                                  double* __restrict__ partial) {
  const int b = blockIdx.x;
  const int lane = threadIdx.x;  // single wave per block

  __shared__ double uofc[N + 1];   // u of the row assigned to column j (2-way banked)
  __shared__ float2 cofc[N + 1];   // pred coords of that row
  __shared__ int pcol[N + 1];      // column -> assigned row (1-indexed), 0 = free

  // Read-only per-lane data: columns j-1 = lane+64k; rows r-1 = lane+64k.
  float tx[4], ty[4], rpx[4], rpy[4];
  double v[4];   // true column duals (owner-lane)
  double sv[4];  // scan duals: = v[k] when free, -inf when marked this row

  const float2* pv = (const float2*)pred + (size_t)b * N;
  const float2* tv = (const float2*)target + (size_t)b * N;
#pragma unroll
  for (int k = 0; k < 4; ++k) {
    int idx = lane + 64 * k;
    float2 pp = pv[idx];
    rpx[k] = pp.x; rpy[k] = pp.y;
    float2 tt = tv[idx];
    tx[k] = tt.x; ty[k] = tt.y;
    v[k] = 0.0; sv[k] = 0.0;
  }
#pragma unroll
  for (int k = 0; k < 5; ++k) {
    int j = lane + 64 * k;
    if (j < N + 1) { uofc[j] = 0.0; cofc[j] = make_float2(0.f, 0.f); pcol[j] = 0; }
  }
  __syncthreads();

  for (int i = 1; i <= N; ++i) {
    // wave-uniform mark masks: bit 'lane' of ml_k <=> column 1+lane+64k marked
    unsigned long long ml0 = 0, ml1 = 0, ml2 = 0, ml3 = 0;
    double uv0 = 0.0;  // live u[i] (virtual column 0), wave-uniform
    double ui0 = 0.0;  // row-start u of current i0; row i itself starts at 0
    float pxi, pyi, rix, riy;
    {
      const int rl = (i - 1) & 63, rs = (i - 1) >> 6;
      pxi = i2f(__builtin_amdgcn_readlane(
          rs == 0 ? f2i(rpx[0]) : rs == 1 ? f2i(rpx[1]) : rs == 2 ? f2i(rpx[2]) : f2i(rpx[3]), rl));
      pyi = i2f(__builtin_amdgcn_readlane(
          rs == 0 ? f2i(rpy[0]) : rs == 1 ? f2i(rpy[1]) : rs == 2 ? f2i(rpy[2]) : f2i(rpy[3]), rl));
      rix = pxi; riy = pyi;  // saved for the augment store
    }

    int jfin;
    while (true) {
      // ---- scan ALL my columns, maskless: marked have sv=-inf -> m=+inf
      double m[4];
#pragma unroll
      for (int k = 0; k < 4; ++k) {
        float dx = pxi - tx[k];
        float dy = pyi - ty[k];
        float c = sqrtf(dx * dx + dy * dy);
        m[k] = ((double)c - ui0) - sv[k];  // reference rounding order (free cols)
      }
      double bm = fmin(fmin(m[0], m[1]), fmin(m[2], m[3]));

      // ---- wave value-min entirely in DPP: 4 butterfly stages + 2 bcast
      DPP_MIN_STAGE(0xB1, 0xF);   // quad_perm [1,0,3,2]  (xor 1)
      DPP_MIN_STAGE(0x4E, 0xF);   // quad_perm [2,3,0,1]  (xor 2)
      DPP_MIN_STAGE(0x141, 0xF);  // row_half_mirror      (xor 4)
      DPP_MIN_STAGE(0x140, 0xF);  // row_mirror           (xor 8)
      DPP_MIN_STAGE(0x142, 0xA);  // row_bcast15 -> rows 1,3
      DPP_MIN_STAGE(0x143, 0xC);  // row_bcast31 -> rows 2,3
      // global min in lane 63; broadcast via SGPRs. delta == gmin bitwise.
      const double delta = mkd(__builtin_amdgcn_readlane(dlo(bm), 63),
                               __builtin_amdgcn_readlane(dhi(bm), 63));

      // ---- argmin j (first-index): k-major ballots == ascending j
      const unsigned long long b0 = __ballot(m[0] == delta);
      const unsigned long long b1 = __ballot(m[1] == delta);
      const unsigned long long b2 = __ballot(m[2] == delta);
      const unsigned long long b3 = __ballot(m[3] == delta);
      const int ks = b0 ? 0 : (b1 ? 1 : (b2 ? 2 : 3));
      const unsigned long long bb = b0 ? b0 : (b1 ? b1 : (b2 ? b2 : b3));
      const int ls = __ffsll(bb) - 1;
      const int j1 = 1 + ls + 64 * ks;

      // ---- path-follow reads: 3 PARALLEL uniform LDS loads (one waitcnt).
      // j1 is unmarked => untouched by this row's uofc RMWs => stable.
      const double uj1 = uofc[j1];
      const float2 cj1 = cofc[j1];
      const int pcolj = pcol[j1];

      // ---- dual update (exact sequential rounding; marked columns only,
      //      excluded from scans => off the critical path, under LDS latency)
      uv0 += delta;  // u[i] via virtual column 0 (marked from step 1)
#pragma unroll
      for (int k = 0; k < 4; ++k) {
        const unsigned long long ml = k == 0 ? ml0 : k == 1 ? ml1 : k == 2 ? ml2 : ml3;
        if ((ml >> lane) & 1) {
          v[k] -= delta;
          uofc[1 + lane + 64 * k] += delta;  // owner-partitioned RMW, 2-way banked
        }
      }

      if (pcolj == 0) { jfin = j1; break; }

      // ---- mark j1: wave-uniform mask update + owner-lane sv = -inf
      {
        const unsigned long long bit = 1ull << ls;
        if (ks == 0) ml0 |= bit; else if (ks == 1) ml1 |= bit;
        else if (ks == 2) ml2 |= bit; else ml3 |= bit;
      }
      if (lane == ls) {
        if (ks == 0) sv[0] = -__builtin_huge_val();
        else if (ks == 1) sv[1] = -__builtin_huge_val();
        else if (ks == 2) sv[2] = -__builtin_huge_val();
        else sv[3] = -__builtin_huge_val();
      }
      // ---- hop to j1's row: row-start u + coords (from the parallel reads)
      ui0 = uj1;
      pxi = cj1.x; pyi = cj1.y;
      __builtin_amdgcn_wave_barrier();
    }

    // ---- augment + publish row i's state under its new column (uniform stores)
    pcol[jfin] = i;
    uofc[jfin] = uv0;
    cofc[jfin] = make_float2(rix, riy);
    // ---- restore scan duals for next row (all columns unmarked again)
#pragma unroll
    for (int k = 0; k < 4; ++k) sv[k] = v[k];
    __builtin_amdgcn_wave_barrier();  // single-wave block: program-order LDS
  }

  __syncthreads();
  // ---- partial MSE: column j matched to row pcol[j]; its coords are in cofc
  double s = 0.0;
#pragma unroll
  for (int k = 0; k < 4; ++k) {
    int j = 1 + lane + 64 * k;
    float2 t = cofc[j];
    double dx = (double)t.x - (double)tx[k];
    double dy = (double)t.y - (double)ty[k];
    s += dx * dx + dy * dy;
  }
#pragma unroll
  for (int off = 1; off < 64; off <<= 1) s += __shfl_xor(s, off);
  if (lane == 0) partial[b] = s;
}

__global__ __launch_bounds__(64) void reduce_kernel(const double* __restrict__ partial,
                                                    float* __restrict__ out, int B) {
  double s = 0.0;
  for (int i = threadIdx.x; i < B; i += 64) s += partial[i];
#pragma unroll
  for (int off = 1; off < 64; off <<= 1) s += __shfl_xor(s, off);
  if (threadIdx.x == 0) out[0] = (float)(s / (double)(B * N * 2));
}

extern "C" void kernel_launch(void* const* d_in, const int* in_sizes, int n_in,
                              void* d_out, int out_size, void* d_ws, size_t ws_size,
                              hipStream_t stream) {
  const float* pred = (const float*)d_in[0];
  const float* target = (const float*)d_in[1];
  float* out = (float*)d_out;
  double* partial = (double*)d_ws;

  const int B = in_sizes[0] / (N * 2);  // 32

  hipLaunchKernelGGL(hung_kernel, dim3(B), dim3(64), 0, stream, pred, target, partial);
  hipLaunchKernelGGL(reduce_kernel, dim3(1), dim3(64), 0, stream, partial, out, B);
}

// Round 12
// 1076.081 us; speedup vs baseline: 1.1017x; 1.1017x over previous
//
#include <hip/hip_runtime.h>
#include <math.h>

// Hungarian (reference-exact degenerate JV) + MSE.
// Anchored on r11 (bit-exact, 1185us). Changes vs r11:
//   * pcol[] DELETED: free/assigned tracked in wave-uniform SGPR masks am0..3
//     (augment-time |=). Loop-exit test = scalar bit test, no LDS.
//   * per-step uofc RMW DELETED: u-accumulation for marked columns lives in
//     owner-lane registers uacc[k] (init = hop.u, a wave-uniform value, at
//     mark time; masked += delta per step -> exact reference rounding order),
//     flushed to LDS once per row (owner-partitioned b64 store). Hop reads
//     touch only UNMARKED columns (stable since a previous row's flush).
//   * {u,cx,cy} re-packed into one 16B struct -> per-step LDS = ONE uniform
//     ds_read_b128, issued before the dual-update VALU (latency hidden).
// HARD RULE (r2/r3/r9): cross-lane mutable state crosses lanes ONLY via LDS
// live reads; readlane only for read-only data or same-step temporaries.
// DPP value-min + delta==gmin + k-major ballots: r8-proven.

#define N 256

static __device__ __forceinline__ int f2i(float x) { union { float f; int i; } u; u.f = x; return u.i; }
static __device__ __forceinline__ float i2f(int x) { union { float f; int i; } u; u.i = x; return u.f; }
static __device__ __forceinline__ double mkd(int lo, int hi) {
  union { unsigned long long u; double d; } w;
  w.u = (((unsigned long long)(unsigned)hi) << 32) | (unsigned)lo;
  return w.d;
}
static __device__ __forceinline__ int dlo(double d) { union { double d; unsigned long long u; } w; w.d = d; return (int)(unsigned)w.u; }
static __device__ __forceinline__ int dhi(double d) { union { double d; unsigned long long u; } w; w.d = d; return (int)(unsigned)(w.u >> 32); }

// One DPP f64-min stage with LITERAL ctrl/row_mask. Masked-out lanes keep
// their own bm (old operand). fmin == strict-< select for NaN-free values.
#define DPP_MIN_STAGE(CTRL, RMASK)                                              \
  {                                                                             \
    int mlo = dlo(bm), mhi = dhi(bm);                                           \
    int slo = __builtin_amdgcn_update_dpp(mlo, mlo, CTRL, RMASK, 0xF, false);   \
    int shi = __builtin_amdgcn_update_dpp(mhi, mhi, CTRL, RMASK, 0xF, false);   \
    bm = fmin(bm, mkd(slo, shi));                                               \
  }

struct alignas(16) UC { double u; float cx, cy; };  // one ds_read_b128

__global__ __launch_bounds__(64) void hung_kernel(const float* __restrict__ pred,
                                                  const float* __restrict__ target,
                                                  double* __restrict__ partial) {
  const int b = blockIdx.x;
  const int lane = threadIdx.x;  // single wave per block

  __shared__ UC ucofc[N + 1];  // per column: {u of its row, row pred coords}

  // Read-only per-lane data: columns j-1 = lane+64k; rows r-1 = lane+64k.
  float tx[4], ty[4], rpx[4], rpy[4];
  double v[4];     // true column duals (owner-lane)
  double sv[4];    // scan duals: = v[k] when free, -inf when marked this row
  double uacc[4];  // in-register u accumulator for columns marked this row

  const float2* pv = (const float2*)pred + (size_t)b * N;
  const float2* tv = (const float2*)target + (size_t)b * N;
#pragma unroll
  for (int k = 0; k < 4; ++k) {
    int idx = lane + 64 * k;
    float2 pp = pv[idx];
    rpx[k] = pp.x; rpy[k] = pp.y;
    float2 tt = tv[idx];
    tx[k] = tt.x; ty[k] = tt.y;
    v[k] = 0.0; sv[k] = 0.0; uacc[k] = 0.0;
  }
#pragma unroll
  for (int k = 0; k < 5; ++k) {
    int j = lane + 64 * k;
    if (j < N + 1) { UC z; z.u = 0.0; z.cx = 0.f; z.cy = 0.f; ucofc[j] = z; }
  }
  __syncthreads();

  // wave-uniform assigned-column masks (bit 'lane' of am_k <=> col 1+lane+64k)
  unsigned long long am0 = 0, am1 = 0, am2 = 0, am3 = 0;

  for (int i = 1; i <= N; ++i) {
    // wave-uniform this-row mark masks
    unsigned long long ml0 = 0, ml1 = 0, ml2 = 0, ml3 = 0;
    double uv0 = 0.0;  // live u[i] (virtual column 0), wave-uniform
    double ui0 = 0.0;  // row-start u of current i0; row i itself starts at 0
    float pxi, pyi, rix, riy;
    {
      const int rl = (i - 1) & 63, rs = (i - 1) >> 6;
      pxi = i2f(__builtin_amdgcn_readlane(
          rs == 0 ? f2i(rpx[0]) : rs == 1 ? f2i(rpx[1]) : rs == 2 ? f2i(rpx[2]) : f2i(rpx[3]), rl));
      pyi = i2f(__builtin_amdgcn_readlane(
          rs == 0 ? f2i(rpy[0]) : rs == 1 ? f2i(rpy[1]) : rs == 2 ? f2i(rpy[2]) : f2i(rpy[3]), rl));
      rix = pxi; riy = pyi;  // saved for the augment store
    }

    int jfin;
    while (true) {
      // ---- scan ALL my columns, maskless: marked have sv=-inf -> m=+inf
      double m[4];
#pragma unroll
      for (int k = 0; k < 4; ++k) {
        float dx = pxi - tx[k];
        float dy = pyi - ty[k];
        float c = sqrtf(dx * dx + dy * dy);
        m[k] = ((double)c - ui0) - sv[k];  // reference rounding order (free cols)
      }
      double bm = fmin(fmin(m[0], m[1]), fmin(m[2], m[3]));

      // ---- wave value-min entirely in DPP: 4 butterfly stages + 2 bcast
      DPP_MIN_STAGE(0xB1, 0xF);   // quad_perm [1,0,3,2]  (xor 1)
      DPP_MIN_STAGE(0x4E, 0xF);   // quad_perm [2,3,0,1]  (xor 2)
      DPP_MIN_STAGE(0x141, 0xF);  // row_half_mirror      (xor 4)
      DPP_MIN_STAGE(0x140, 0xF);  // row_mirror           (xor 8)
      DPP_MIN_STAGE(0x142, 0xA);  // row_bcast15 -> rows 1,3
      DPP_MIN_STAGE(0x143, 0xC);  // row_bcast31 -> rows 2,3
      // global min in lane 63; broadcast via SGPRs. delta == gmin bitwise.
      const double delta = mkd(__builtin_amdgcn_readlane(dlo(bm), 63),
                               __builtin_amdgcn_readlane(dhi(bm), 63));

      // ---- argmin j (first-index): k-major ballots == ascending j
      const unsigned long long b0 = __ballot(m[0] == delta);
      const unsigned long long b1 = __ballot(m[1] == delta);
      const unsigned long long b2 = __ballot(m[2] == delta);
      const unsigned long long b3 = __ballot(m[3] == delta);
      const int ks = b0 ? 0 : (b1 ? 1 : (b2 ? 2 : 3));
      const unsigned long long bb = b0 ? b0 : (b1 ? b1 : (b2 ? b2 : b3));
      const int ls = __ffsll(bb) - 1;
      const int j1 = 1 + ls + 64 * ks;

      // ---- issue the ONLY per-step LDS op early; dual-update hides latency.
      // (j1 unmarked => its entry is stable; harmless if this is the exit.)
      const UC hop = ucofc[j1];

      // ---- dual update (exact sequential rounding; marked columns only)
      uv0 += delta;  // u[i] via virtual column 0 (marked from step 1)
#pragma unroll
      for (int k = 0; k < 4; ++k) {
        const unsigned long long ml = k == 0 ? ml0 : k == 1 ? ml1 : k == 2 ? ml2 : ml3;
        const double add = ((ml >> lane) & 1) ? delta : 0.0;
        v[k] -= add;
        uacc[k] += add;
      }

      // ---- loop exit: pure scalar bit test on assigned-masks (no LDS)
      const unsigned long long am = ks == 0 ? am0 : ks == 1 ? am1 : ks == 2 ? am2 : am3;
      if (!((am >> ls) & 1)) { jfin = j1; break; }

      // ---- mark j1: mask bit + owner-lane sv=-inf, uacc=hop.u (uniform value)
      {
        const unsigned long long bit = 1ull << ls;
        if (ks == 0) ml0 |= bit; else if (ks == 1) ml1 |= bit;
        else if (ks == 2) ml2 |= bit; else ml3 |= bit;
      }
      if (lane == ls) {
        if (ks == 0)      { sv[0] = -__builtin_huge_val(); uacc[0] = hop.u; }
        else if (ks == 1) { sv[1] = -__builtin_huge_val(); uacc[1] = hop.u; }
        else if (ks == 2) { sv[2] = -__builtin_huge_val(); uacc[2] = hop.u; }
        else              { sv[3] = -__builtin_huge_val(); uacc[3] = hop.u; }
      }
      // ---- hop to j1's row: row-start u + coords (from the b128 read)
      ui0 = hop.u;
      pxi = hop.cx; pyi = hop.cy;
      __builtin_amdgcn_wave_barrier();
    }

    // ---- augment: record assignment in SGPR mask + publish row i's state
    {
      const int fl = (jfin - 1) & 63, fs = (jfin - 1) >> 6;
      const unsigned long long bit = 1ull << fl;
      if (fs == 0) am0 |= bit; else if (fs == 1) am1 |= bit;
      else if (fs == 2) am2 |= bit; else am3 |= bit;
    }
    UC nu; nu.u = uv0; nu.cx = rix; nu.cy = riy;
    ucofc[jfin] = nu;  // wave-uniform b128 store
    // ---- flush this row's marked-column u values (owner-partitioned stores)
#pragma unroll
    for (int k = 0; k < 4; ++k) {
      const unsigned long long ml = k == 0 ? ml0 : k == 1 ? ml1 : k == 2 ? ml2 : ml3;
      if ((ml >> lane) & 1) ucofc[1 + lane + 64 * k].u = uacc[k];
    }
    // ---- restore scan duals (all columns unmarked again)
#pragma unroll
    for (int k = 0; k < 4; ++k) sv[k] = v[k];
    __builtin_amdgcn_wave_barrier();  // single-wave block: program-order LDS
  }

  __syncthreads();
  // ---- partial MSE: column j's matched row coords are in ucofc[j]
  double s = 0.0;
#pragma unroll
  for (int k = 0; k < 4; ++k) {
    int j = 1 + lane + 64 * k;
    UC t = ucofc[j];
    double dx = (double)t.cx - (double)tx[k];
    double dy = (double)t.cy - (double)ty[k];
    s += dx * dx + dy * dy;
  }
#pragma unroll
  for (int off = 1; off < 64; off <<= 1) s += __shfl_xor(s, off);
  if (lane == 0) partial[b] = s;
}

__global__ __launch_bounds__(64) void reduce_kernel(const double* __restrict__ partial,
                                                    float* __restrict__ out, int B) {
  double s = 0.0;
  for (int i = threadIdx.x; i < B; i += 64) s += partial[i];
#pragma unroll
  for (int off = 1; off < 64; off <<= 1) s += __shfl_xor(s, off);
  if (threadIdx.x == 0) out[0] = (float)(s / (double)(B * N * 2));
}

extern "C" void kernel_launch(void* const* d_in, const int* in_sizes, int n_in,
                              void* d_out, int out_size, void* d_ws, size_t ws_size,
                              hipStream_t stream) {
  const float* pred = (const float*)d_in[0];
  const float* target = (const float*)d_in[1];
  float* out = (float*)d_out;
  double* partial = (double*)d_ws;

  const int B = in_sizes[0] / (N * 2);  // 32

  hipLaunchKernelGGL(hung_kernel, dim3(B), dim3(64), 0, stream, pred, target, partial);
  hipLaunchKernelGGL(reduce_kernel, dim3(1), dim3(64), 0, stream, partial, out, B);
}

// Round 13
// 1008.277 us; speedup vs baseline: 1.1757x; 1.0672x over previous
//
#include <hip/hip_runtime.h>
#include <math.h>

// Hungarian (reference-exact degenerate JV) + MSE.
// Anchored on r12 (bit-exact, 1076us). Changes vs r12 (all value-preserving):
//   * uacc seed ELIMINATED via invariant: uacc[k] == "u of my column's
//     assigned row" at every row boundary (init 0 = LDS init; masked += delta
//     while marked = exact reference sequence; = uv0 at augment; flushed to
//     LDS each row-end). At mark time uacc[k] already equals ucofc[j1].u, so
//     the seed (the only early hop.u consumer) is redundant -> the hop's
//     lgkmcnt wait sinks to the next scan; dual-update+mark covers the LDS
//     latency.
//   * branchless mark: sv[k] = (k==ks && lane==ls) ? -inf : sv[k] (cndmask,
//     no exec-divergent block).
//   * flush = 4 UNCONDITIONAL ds_write_b64 (owner-partitioned; same-value
//     writes for unmarked/free columns are harmless). Augment uacc set via
//     cndmask of wave-uniform uv0.
//   * inner wave_barrier deleted (loop's only LDS op is a read of
//     augment-stable data; single-wave DS ops are program-ordered). Row-end
//     barrier kept.
// HARD RULE (r2/r3/r9): cross-lane mutable state crosses lanes ONLY via LDS
// live reads; readlane only for read-only data or same-step temporaries.
// DPP value-min + delta==gmin + k-major ballots: r8-proven.

#define N 256

static __device__ __forceinline__ int f2i(float x) { union { float f; int i; } u; u.f = x; return u.i; }
static __device__ __forceinline__ float i2f(int x) { union { float f; int i; } u; u.i = x; return u.f; }
static __device__ __forceinline__ double mkd(int lo, int hi) {
  union { unsigned long long u; double d; } w;
  w.u = (((unsigned long long)(unsigned)hi) << 32) | (unsigned)lo;
  return w.d;
}
static __device__ __forceinline__ int dlo(double d) { union { double d; unsigned long long u; } w; w.d = d; return (int)(unsigned)w.u; }
static __device__ __forceinline__ int dhi(double d) { union { double d; unsigned long long u; } w; w.d = d; return (int)(unsigned)(w.u >> 32); }

// One DPP f64-min stage with LITERAL ctrl/row_mask. Masked-out lanes keep
// their own bm (old operand). fmin == strict-< select for NaN-free values.
#define DPP_MIN_STAGE(CTRL, RMASK)                                              \
  {                                                                             \
    int mlo = dlo(bm), mhi = dhi(bm);                                           \
    int slo = __builtin_amdgcn_update_dpp(mlo, mlo, CTRL, RMASK, 0xF, false);   \
    int shi = __builtin_amdgcn_update_dpp(mhi, mhi, CTRL, RMASK, 0xF, false);   \
    bm = fmin(bm, mkd(slo, shi));                                               \
  }

struct alignas(16) UC { double u; float cx, cy; };  // one ds_read_b128

__global__ __launch_bounds__(64) void hung_kernel(const float* __restrict__ pred,
                                                  const float* __restrict__ target,
                                                  double* __restrict__ partial) {
  const int b = blockIdx.x;
  const int lane = threadIdx.x;  // single wave per block

  __shared__ UC ucofc[N + 1];  // per column: {u of its row, row pred coords}

  // Read-only per-lane data: columns j-1 = lane+64k; rows r-1 = lane+64k.
  float tx[4], ty[4], rpx[4], rpy[4];
  double v[4];     // true column duals (owner-lane)
  double sv[4];    // scan duals: = v[k] when free, -inf when marked this row
  double uacc[4];  // INVARIANT: u of my column's assigned row (0 if free)

  const float2* pv = (const float2*)pred + (size_t)b * N;
  const float2* tv = (const float2*)target + (size_t)b * N;
#pragma unroll
  for (int k = 0; k < 4; ++k) {
    int idx = lane + 64 * k;
    float2 pp = pv[idx];
    rpx[k] = pp.x; rpy[k] = pp.y;
    float2 tt = tv[idx];
    tx[k] = tt.x; ty[k] = tt.y;
    v[k] = 0.0; sv[k] = 0.0; uacc[k] = 0.0;
  }
#pragma unroll
  for (int k = 0; k < 5; ++k) {
    int j = lane + 64 * k;
    if (j < N + 1) { UC z; z.u = 0.0; z.cx = 0.f; z.cy = 0.f; ucofc[j] = z; }
  }
  __syncthreads();

  // wave-uniform assigned-column masks (bit 'lane' of am_k <=> col 1+lane+64k)
  unsigned long long am0 = 0, am1 = 0, am2 = 0, am3 = 0;
  const double NINF = -__builtin_huge_val();

  for (int i = 1; i <= N; ++i) {
    // wave-uniform this-row mark masks
    unsigned long long ml0 = 0, ml1 = 0, ml2 = 0, ml3 = 0;
    double uv0 = 0.0;  // live u[i] (virtual column 0), wave-uniform
    double ui0 = 0.0;  // row-start u of current i0; row i itself starts at 0
    float pxi, pyi, rix, riy;
    {
      const int rl = (i - 1) & 63, rs = (i - 1) >> 6;
      pxi = i2f(__builtin_amdgcn_readlane(
          rs == 0 ? f2i(rpx[0]) : rs == 1 ? f2i(rpx[1]) : rs == 2 ? f2i(rpx[2]) : f2i(rpx[3]), rl));
      pyi = i2f(__builtin_amdgcn_readlane(
          rs == 0 ? f2i(rpy[0]) : rs == 1 ? f2i(rpy[1]) : rs == 2 ? f2i(rpy[2]) : f2i(rpy[3]), rl));
      rix = pxi; riy = pyi;  // saved for the augment store
    }

    int jfin;
    while (true) {
      // ---- scan ALL my columns, maskless: marked have sv=-inf -> m=+inf
      double m[4];
#pragma unroll
      for (int k = 0; k < 4; ++k) {
        float dx = pxi - tx[k];
        float dy = pyi - ty[k];
        float c = sqrtf(dx * dx + dy * dy);
        m[k] = ((double)c - ui0) - sv[k];  // reference rounding order (free cols)
      }
      double bm = fmin(fmin(m[0], m[1]), fmin(m[2], m[3]));

      // ---- wave value-min entirely in DPP: 4 butterfly stages + 2 bcast
      DPP_MIN_STAGE(0xB1, 0xF);   // quad_perm [1,0,3,2]  (xor 1)
      DPP_MIN_STAGE(0x4E, 0xF);   // quad_perm [2,3,0,1]  (xor 2)
      DPP_MIN_STAGE(0x141, 0xF);  // row_half_mirror      (xor 4)
      DPP_MIN_STAGE(0x140, 0xF);  // row_mirror           (xor 8)
      DPP_MIN_STAGE(0x142, 0xA);  // row_bcast15 -> rows 1,3
      DPP_MIN_STAGE(0x143, 0xC);  // row_bcast31 -> rows 2,3
      // global min in lane 63; broadcast via SGPRs. delta == gmin bitwise.
      const double delta = mkd(__builtin_amdgcn_readlane(dlo(bm), 63),
                               __builtin_amdgcn_readlane(dhi(bm), 63));

      // ---- argmin j (first-index): k-major ballots == ascending j
      const unsigned long long b0 = __ballot(m[0] == delta);
      const unsigned long long b1 = __ballot(m[1] == delta);
      const unsigned long long b2 = __ballot(m[2] == delta);
      const unsigned long long b3 = __ballot(m[3] == delta);
      const int ks = b0 ? 0 : (b1 ? 1 : (b2 ? 2 : 3));
      const unsigned long long bb = b0 ? b0 : (b1 ? b1 : (b2 ? b2 : b3));
      const int ls = __ffsll(bb) - 1;
      const int j1 = 1 + ls + 64 * ks;

      // ---- issue the ONLY per-step LDS op; no consumer until next scan
      // (j1 unmarked => entry stable; free-j1 entry is {0,0,0}, harmless)
      const UC hop = ucofc[j1];

      // ---- dual update (exact sequential rounding; marked columns only)
      uv0 += delta;  // u[i] via virtual column 0 (marked from step 1)
#pragma unroll
      for (int k = 0; k < 4; ++k) {
        const unsigned long long ml = k == 0 ? ml0 : k == 1 ? ml1 : k == 2 ? ml2 : ml3;
        const double add = ((ml >> lane) & 1) ? delta : 0.0;
        v[k] -= add;
        uacc[k] += add;  // invariant: tracks u of my column's row while marked
      }

      // ---- loop exit: pure scalar bit test on assigned-masks (no LDS)
      const unsigned long long am = ks == 0 ? am0 : ks == 1 ? am1 : ks == 2 ? am2 : am3;
      if (!((am >> ls) & 1)) { jfin = j1; break; }

      // ---- mark j1: scalar mask bit + branchless owner-lane sv = -inf
      {
        const unsigned long long bit = 1ull << ls;
        if (ks == 0) ml0 |= bit; else if (ks == 1) ml1 |= bit;
        else if (ks == 2) ml2 |= bit; else ml3 |= bit;
      }
      const bool hit = (lane == ls);
#pragma unroll
      for (int k = 0; k < 4; ++k) {
        const bool selk = hit && (ks == k);
        sv[k] = selk ? NINF : sv[k];  // cndmask; no uacc seed needed (invariant)
      }
      // ---- hop to j1's row (waitcnt sinks to next scan's first use)
      ui0 = hop.u;
      pxi = hop.cx; pyi = hop.cy;
    }

    // ---- augment: record assignment + set uacc invariant for jfin's owner
    {
      const int fl = (jfin - 1) & 63, fs = (jfin - 1) >> 6;
      const unsigned long long bit = 1ull << fl;
      if (fs == 0) am0 |= bit; else if (fs == 1) am1 |= bit;
      else if (fs == 2) am2 |= bit; else am3 |= bit;
      const bool ahit = (lane == fl);
#pragma unroll
      for (int k = 0; k < 4; ++k) {
        const bool selk = ahit && (fs == k);
        uacc[k] = selk ? uv0 : uacc[k];  // cndmask of wave-uniform value
      }
    }
    UC nu; nu.u = uv0; nu.cx = rix; nu.cy = riy;
    ucofc[jfin] = nu;  // wave-uniform b128 store (coords for future hops/MSE)
    // ---- flush invariant: unconditional owner-partitioned b64 stores
#pragma unroll
    for (int k = 0; k < 4; ++k) ucofc[1 + lane + 64 * k].u = uacc[k];
    // ---- restore scan duals (all columns unmarked again)
#pragma unroll
    for (int k = 0; k < 4; ++k) sv[k] = v[k];
    __builtin_amdgcn_wave_barrier();  // row-end ordering point (free)
  }

  __syncthreads();
  // ---- partial MSE: column j's matched row coords are in ucofc[j]
  double s = 0.0;
#pragma unroll
  for (int k = 0; k < 4; ++k) {
    int j = 1 + lane + 64 * k;
    UC t = ucofc[j];
    double dx = (double)t.cx - (double)tx[k];
    double dy = (double)t.cy - (double)ty[k];
    s += dx * dx + dy * dy;
  }
#pragma unroll
  for (int off = 1; off < 64; off <<= 1) s += __shfl_xor(s, off);
  if (lane == 0) partial[b] = s;
}

__global__ __launch_bounds__(64) void reduce_kernel(const double* __restrict__ partial,
                                                    float* __restrict__ out, int B) {
  double s = 0.0;
  for (int i = threadIdx.x; i < B; i += 64) s += partial[i];
#pragma unroll
  for (int off = 1; off < 64; off <<= 1) s += __shfl_xor(s, off);
  if (threadIdx.x == 0) out[0] = (float)(s / (double)(B * N * 2));
}

extern "C" void kernel_launch(void* const* d_in, const int* in_sizes, int n_in,
                              void* d_out, int out_size, void* d_ws, size_t ws_size,
                              hipStream_t stream) {
  const float* pred = (const float*)d_in[0];
  const float* target = (const float*)d_in[1];
  float* out = (float*)d_out;
  double* partial = (double*)d_ws;

  const int B = in_sizes[0] / (N * 2);  // 32

  hipLaunchKernelGGL(hung_kernel, dim3(B), dim3(64), 0, stream, pred, target, partial);
  hipLaunchKernelGGL(reduce_kernel, dim3(1), dim3(64), 0, stream, partial, out, B);
}

// Round 14
// 1005.903 us; speedup vs baseline: 1.1785x; 1.0024x over previous
//
#include <hip/hip_runtime.h>
#include <math.h>

// Hungarian (reference-exact degenerate JV) + MSE.
// Anchored on r13 (bit-exact, 1008us). Changes vs r13 (value-preserving):
//   * reduction tail: DPP row_bcast15/31 (lane-63-only result + 2x readlane
//     SGPR round-trip) -> gfx950 v_permlane16_swap / v_permlane32_swap
//     butterfly stages. r = permlane_swap(x,x) yields both half-exchanged
//     words; fmin of the two reassembled doubles == the xor-16/32 stage for
//     EVERY lane (symmetric in r[0]/r[1], so swap-direction ambiguity is
//     harmless). Global min ends in ALL lanes as VGPR -> delta = bm, no
//     readlane, no VALU->SALU->VALU hazard on the chain. Ballots compare
//     against the (uniform) VGPR directly.
//   * scalar step-guard (N+2 cap, off-chain) -> a semantics surprise fails
//     fast as wrong-answer instead of hanging; (ls&63) keeps shifts defined.
//   * __has_builtin fallback to the r13 bcast+readlane path.
// HARD RULE (r2/r3/r9): cross-lane mutable state crosses lanes ONLY via LDS
// live reads; readlane only for read-only data or same-step temporaries.

#define N 256

static __device__ __forceinline__ int f2i(float x) { union { float f; int i; } u; u.f = x; return u.i; }
static __device__ __forceinline__ float i2f(int x) { union { float f; int i; } u; u.i = x; return u.f; }
static __device__ __forceinline__ double mkd(int lo, int hi) {
  union { unsigned long long u; double d; } w;
  w.u = (((unsigned long long)(unsigned)hi) << 32) | (unsigned)lo;
  return w.d;
}
static __device__ __forceinline__ int dlo(double d) { union { double d; unsigned long long u; } w; w.d = d; return (int)(unsigned)w.u; }
static __device__ __forceinline__ int dhi(double d) { union { double d; unsigned long long u; } w; w.d = d; return (int)(unsigned)(w.u >> 32); }

#if __has_builtin(__builtin_amdgcn_permlane16_swap) && __has_builtin(__builtin_amdgcn_permlane32_swap)
#define HAVE_PL_SWAP 1
#else
#define HAVE_PL_SWAP 0
#endif

// One DPP f64-min stage with LITERAL ctrl/row_mask. Masked-out lanes keep
// their own bm (old operand). fmin == strict-< select for NaN-free values.
#define DPP_MIN_STAGE(CTRL, RMASK)                                              \
  {                                                                             \
    int mlo = dlo(bm), mhi = dhi(bm);                                           \
    int slo = __builtin_amdgcn_update_dpp(mlo, mlo, CTRL, RMASK, 0xF, false);   \
    int shi = __builtin_amdgcn_update_dpp(mhi, mhi, CTRL, RMASK, 0xF, false);   \
    bm = fmin(bm, mkd(slo, shi));                                               \
  }

struct alignas(16) UC { double u; float cx, cy; };  // one ds_read_b128

__global__ __launch_bounds__(64) void hung_kernel(const float* __restrict__ pred,
                                                  const float* __restrict__ target,
                                                  double* __restrict__ partial) {
  const int b = blockIdx.x;
  const int lane = threadIdx.x;  // single wave per block

  __shared__ UC ucofc[N + 1];  // per column: {u of its row, row pred coords}

  // Read-only per-lane data: columns j-1 = lane+64k; rows r-1 = lane+64k.
  float tx[4], ty[4], rpx[4], rpy[4];
  double v[4];     // true column duals (owner-lane)
  double sv[4];    // scan duals: = v[k] when free, -inf when marked this row
  double uacc[4];  // INVARIANT: u of my column's assigned row (0 if free)

  const float2* pv = (const float2*)pred + (size_t)b * N;
  const float2* tv = (const float2*)target + (size_t)b * N;
#pragma unroll
  for (int k = 0; k < 4; ++k) {
    int idx = lane + 64 * k;
    float2 pp = pv[idx];
    rpx[k] = pp.x; rpy[k] = pp.y;
    float2 tt = tv[idx];
    tx[k] = tt.x; ty[k] = tt.y;
    v[k] = 0.0; sv[k] = 0.0; uacc[k] = 0.0;
  }
#pragma unroll
  for (int k = 0; k < 5; ++k) {
    int j = lane + 64 * k;
    if (j < N + 1) { UC z; z.u = 0.0; z.cx = 0.f; z.cy = 0.f; ucofc[j] = z; }
  }
  __syncthreads();

  // wave-uniform assigned-column masks (bit 'lane' of am_k <=> col 1+lane+64k)
  unsigned long long am0 = 0, am1 = 0, am2 = 0, am3 = 0;
  const double NINF = -__builtin_huge_val();

  for (int i = 1; i <= N; ++i) {
    // wave-uniform this-row mark masks
    unsigned long long ml0 = 0, ml1 = 0, ml2 = 0, ml3 = 0;
    double uv0 = 0.0;  // live u[i] (virtual column 0), wave-uniform
    double ui0 = 0.0;  // row-start u of current i0; row i itself starts at 0
    float pxi, pyi, rix, riy;
    {
      const int rl = (i - 1) & 63, rs = (i - 1) >> 6;
      pxi = i2f(__builtin_amdgcn_readlane(
          rs == 0 ? f2i(rpx[0]) : rs == 1 ? f2i(rpx[1]) : rs == 2 ? f2i(rpx[2]) : f2i(rpx[3]), rl));
      pyi = i2f(__builtin_amdgcn_readlane(
          rs == 0 ? f2i(rpy[0]) : rs == 1 ? f2i(rpy[1]) : rs == 2 ? f2i(rpy[2]) : f2i(rpy[3]), rl));
      rix = pxi; riy = pyi;  // saved for the augment store
    }

    int jfin;
    int guard = N + 2;  // fail-fast bound (path length <= N+1); off-chain scalar
    while (true) {
      // ---- scan ALL my columns, maskless: marked have sv=-inf -> m=+inf
      double m[4];
#pragma unroll
      for (int k = 0; k < 4; ++k) {
        float dx = pxi - tx[k];
        float dy = pyi - ty[k];
        float c = sqrtf(dx * dx + dy * dy);
        m[k] = ((double)c - ui0) - sv[k];  // reference rounding order (free cols)
      }
      double bm = fmin(fmin(m[0], m[1]), fmin(m[2], m[3]));

      // ---- wave value-min: 4 DPP butterfly stages + 2 all-lane swap stages
      DPP_MIN_STAGE(0xB1, 0xF);   // quad_perm [1,0,3,2]  (xor 1)
      DPP_MIN_STAGE(0x4E, 0xF);   // quad_perm [2,3,0,1]  (xor 2)
      DPP_MIN_STAGE(0x141, 0xF);  // row_half_mirror      (xor 4)
      DPP_MIN_STAGE(0x140, 0xF);  // row_mirror           (xor 8)
#if HAVE_PL_SWAP
      {  // xor 16 for ALL lanes: min over the unordered swapped pair
        int mlo = dlo(bm), mhi = dhi(bm);
        auto rlo = __builtin_amdgcn_permlane16_swap(mlo, mlo, false, false);
        auto rhi = __builtin_amdgcn_permlane16_swap(mhi, mhi, false, false);
        bm = fmin(mkd(rlo[0], rhi[0]), mkd(rlo[1], rhi[1]));
      }
      {  // xor 32 for ALL lanes
        int mlo = dlo(bm), mhi = dhi(bm);
        auto rlo = __builtin_amdgcn_permlane32_swap(mlo, mlo, false, false);
        auto rhi = __builtin_amdgcn_permlane32_swap(mhi, mhi, false, false);
        bm = fmin(mkd(rlo[0], rhi[0]), mkd(rlo[1], rhi[1]));
      }
      const double delta = bm;  // global min in EVERY lane (VGPR); no readlane
#else
      DPP_MIN_STAGE(0x142, 0xA);  // row_bcast15 -> rows 1,3
      DPP_MIN_STAGE(0x143, 0xC);  // row_bcast31 -> rows 2,3
      const double delta = mkd(__builtin_amdgcn_readlane(dlo(bm), 63),
                               __builtin_amdgcn_readlane(dhi(bm), 63));
#endif

      // ---- argmin j (first-index): k-major ballots == ascending j
      const unsigned long long b0 = __ballot(m[0] == delta);
      const unsigned long long b1 = __ballot(m[1] == delta);
      const unsigned long long b2 = __ballot(m[2] == delta);
      const unsigned long long b3 = __ballot(m[3] == delta);
      const int ks = b0 ? 0 : (b1 ? 1 : (b2 ? 2 : 3));
      const unsigned long long bb = b0 ? b0 : (b1 ? b1 : (b2 ? b2 : b3));
      const int ls = (__ffsll(bb) - 1) & 63;  // defined even if bb==0 (guarded)
      const int j1 = 1 + ls + 64 * ks;

      // ---- issue the ONLY per-step LDS op; no consumer until next scan
      const UC hop = ucofc[j1];

      // ---- dual update (exact sequential rounding; marked columns only)
      uv0 += delta;  // u[i] via virtual column 0 (marked from step 1)
#pragma unroll
      for (int k = 0; k < 4; ++k) {
        const unsigned long long ml = k == 0 ? ml0 : k == 1 ? ml1 : k == 2 ? ml2 : ml3;
        const double add = ((ml >> lane) & 1) ? delta : 0.0;
        v[k] -= add;
        uacc[k] += add;  // invariant: tracks u of my column's row while marked
      }

      // ---- loop exit: scalar bit test on assigned-masks (+ fail-fast guard)
      const unsigned long long am = ks == 0 ? am0 : ks == 1 ? am1 : ks == 2 ? am2 : am3;
      if (!((am >> ls) & 1) || --guard == 0) { jfin = j1; break; }

      // ---- mark j1: scalar mask bit + branchless owner-lane sv = -inf
      {
        const unsigned long long bit = 1ull << ls;
        if (ks == 0) ml0 |= bit; else if (ks == 1) ml1 |= bit;
        else if (ks == 2) ml2 |= bit; else ml3 |= bit;
      }
      const bool hit = (lane == ls);
#pragma unroll
      for (int k = 0; k < 4; ++k) {
        const bool selk = hit && (ks == k);
        sv[k] = selk ? NINF : sv[k];  // cndmask; uacc needs no seed (invariant)
      }
      // ---- hop to j1's row (waitcnt sinks to next scan's first use)
      ui0 = hop.u;
      pxi = hop.cx; pyi = hop.cy;
    }

    // ---- augment: record assignment + set uacc invariant for jfin's owner
    {
      const int fl = (jfin - 1) & 63, fs = ((jfin - 1) >> 6) & 3;
      const unsigned long long bit = 1ull << fl;
      if (fs == 0) am0 |= bit; else if (fs == 1) am1 |= bit;
      else if (fs == 2) am2 |= bit; else am3 |= bit;
      const bool ahit = (lane == fl);
#pragma unroll
      for (int k = 0; k < 4; ++k) {
        const bool selk = ahit && (fs == k);
        uacc[k] = selk ? uv0 : uacc[k];  // cndmask of wave-uniform value
      }
    }
    UC nu; nu.u = uv0; nu.cx = rix; nu.cy = riy;
    ucofc[jfin] = nu;  // wave-uniform b128 store (coords for future hops/MSE)
    // ---- flush invariant: unconditional owner-partitioned b64 stores
#pragma unroll
    for (int k = 0; k < 4; ++k) ucofc[1 + lane + 64 * k].u = uacc[k];
    // ---- restore scan duals (all columns unmarked again)
#pragma unroll
    for (int k = 0; k < 4; ++k) sv[k] = v[k];
    __builtin_amdgcn_wave_barrier();  // row-end ordering point (free)
  }

  __syncthreads();
  // ---- partial MSE: column j's matched row coords are in ucofc[j]
  double s = 0.0;
#pragma unroll
  for (int k = 0; k < 4; ++k) {
    int j = 1 + lane + 64 * k;
    UC t = ucofc[j];
    double dx = (double)t.cx - (double)tx[k];
    double dy = (double)t.cy - (double)ty[k];
    s += dx * dx + dy * dy;
  }
#pragma unroll
  for (int off = 1; off < 64; off <<= 1) s += __shfl_xor(s, off);
  if (lane == 0) partial[b] = s;
}

__global__ __launch_bounds__(64) void reduce_kernel(const double* __restrict__ partial,
                                                    float* __restrict__ out, int B) {
  double s = 0.0;
  for (int i = threadIdx.x; i < B; i += 64) s += partial[i];
#pragma unroll
  for (int off = 1; off < 64; off <<= 1) s += __shfl_xor(s, off);
  if (threadIdx.x == 0) out[0] = (float)(s / (double)(B * N * 2));
}

extern "C" void kernel_launch(void* const* d_in, const int* in_sizes, int n_in,
                              void* d_out, int out_size, void* d_ws, size_t ws_size,
                              hipStream_t stream) {
  const float* pred = (const float*)d_in[0];
  const float* target = (const float*)d_in[1];
  float* out = (float*)d_out;
  double* partial = (double*)d_ws;

  const int B = in_sizes[0] / (N * 2);  // 32

  hipLaunchKernelGGL(hung_kernel, dim3(B), dim3(64), 0, stream, pred, target, partial);
  hipLaunchKernelGGL(reduce_kernel, dim3(1), dim3(64), 0, stream, partial, out, B);
}

// Round 15
// 769.366 us; speedup vs baseline: 1.5408x; 1.3074x over previous
//
#include <hip/hip_runtime.h>
#include <math.h>

// Hungarian (reference-exact degenerate JV) + MSE.
// Anchored on r14 (bit-exact, 1006us). ONE change vs r14:
//   * sqrtf -> __builtin_amdgcn_sqrtf (raw v_sqrt_f32). The IEEE sqrtf
//     expansion (~10 instrs x 4 columns ~= 80-100cy of issue) sits directly on
//     the per-step critical chain (scan cannot start before the hop ds_read
//     returns). Raw sqrt is <=1ulp; an argmin flip needs the top-2 m-values
//     within ~1ulp of c -> expected O(1) flips total, each perturbing the
//     output by ~1e-3 << 8.4e-3 threshold. REVERT THIS LINE if absmax fails.
// Everything else byte-identical to r14 (DPP value-min + permlane-swap tail
// with fallback, delta==gmin, k-major ballots, SGPR masks, uacc invariant,
// one ds_read_b128 per step, fail-fast guard).
// HARD RULE (r2/r3/r9): cross-lane mutable state crosses lanes ONLY via LDS
// live reads; readlane only for read-only data or same-step temporaries.

#define N 256

static __device__ __forceinline__ int f2i(float x) { union { float f; int i; } u; u.f = x; return u.i; }
static __device__ __forceinline__ float i2f(int x) { union { float f; int i; } u; u.i = x; return u.f; }
static __device__ __forceinline__ double mkd(int lo, int hi) {
  union { unsigned long long u; double d; } w;
  w.u = (((unsigned long long)(unsigned)hi) << 32) | (unsigned)lo;
  return w.d;
}
static __device__ __forceinline__ int dlo(double d) { union { double d; unsigned long long u; } w; w.d = d; return (int)(unsigned)w.u; }
static __device__ __forceinline__ int dhi(double d) { union { double d; unsigned long long u; } w; w.d = d; return (int)(unsigned)(w.u >> 32); }

#if __has_builtin(__builtin_amdgcn_sqrtf)
#define FAST_SQRT(x) __builtin_amdgcn_sqrtf(x)
#else
#define FAST_SQRT(x) sqrtf(x)
#endif

#if __has_builtin(__builtin_amdgcn_permlane16_swap) && __has_builtin(__builtin_amdgcn_permlane32_swap)
#define HAVE_PL_SWAP 1
#else
#define HAVE_PL_SWAP 0
#endif

// One DPP f64-min stage with LITERAL ctrl/row_mask. Masked-out lanes keep
// their own bm (old operand). fmin == strict-< select for NaN-free values.
#define DPP_MIN_STAGE(CTRL, RMASK)                                              \
  {                                                                             \
    int mlo = dlo(bm), mhi = dhi(bm);                                           \
    int slo = __builtin_amdgcn_update_dpp(mlo, mlo, CTRL, RMASK, 0xF, false);   \
    int shi = __builtin_amdgcn_update_dpp(mhi, mhi, CTRL, RMASK, 0xF, false);   \
    bm = fmin(bm, mkd(slo, shi));                                               \
  }

struct alignas(16) UC { double u; float cx, cy; };  // one ds_read_b128

__global__ __launch_bounds__(64) void hung_kernel(const float* __restrict__ pred,
                                                  const float* __restrict__ target,
                                                  double* __restrict__ partial) {
  const int b = blockIdx.x;
  const int lane = threadIdx.x;  // single wave per block

  __shared__ UC ucofc[N + 1];  // per column: {u of its row, row pred coords}

  // Read-only per-lane data: columns j-1 = lane+64k; rows r-1 = lane+64k.
  float tx[4], ty[4], rpx[4], rpy[4];
  double v[4];     // true column duals (owner-lane)
  double sv[4];    // scan duals: = v[k] when free, -inf when marked this row
  double uacc[4];  // INVARIANT: u of my column's assigned row (0 if free)

  const float2* pv = (const float2*)pred + (size_t)b * N;
  const float2* tv = (const float2*)target + (size_t)b * N;
#pragma unroll
  for (int k = 0; k < 4; ++k) {
    int idx = lane + 64 * k;
    float2 pp = pv[idx];
    rpx[k] = pp.x; rpy[k] = pp.y;
    float2 tt = tv[idx];
    tx[k] = tt.x; ty[k] = tt.y;
    v[k] = 0.0; sv[k] = 0.0; uacc[k] = 0.0;
  }
#pragma unroll
  for (int k = 0; k < 5; ++k) {
    int j = lane + 64 * k;
    if (j < N + 1) { UC z; z.u = 0.0; z.cx = 0.f; z.cy = 0.f; ucofc[j] = z; }
  }
  __syncthreads();

  // wave-uniform assigned-column masks (bit 'lane' of am_k <=> col 1+lane+64k)
  unsigned long long am0 = 0, am1 = 0, am2 = 0, am3 = 0;
  const double NINF = -__builtin_huge_val();

  for (int i = 1; i <= N; ++i) {
    // wave-uniform this-row mark masks
    unsigned long long ml0 = 0, ml1 = 0, ml2 = 0, ml3 = 0;
    double uv0 = 0.0;  // live u[i] (virtual column 0), wave-uniform
    double ui0 = 0.0;  // row-start u of current i0; row i itself starts at 0
    float pxi, pyi, rix, riy;
    {
      const int rl = (i - 1) & 63, rs = (i - 1) >> 6;
      pxi = i2f(__builtin_amdgcn_readlane(
          rs == 0 ? f2i(rpx[0]) : rs == 1 ? f2i(rpx[1]) : rs == 2 ? f2i(rpx[2]) : f2i(rpx[3]), rl));
      pyi = i2f(__builtin_amdgcn_readlane(
          rs == 0 ? f2i(rpy[0]) : rs == 1 ? f2i(rpy[1]) : rs == 2 ? f2i(rpy[2]) : f2i(rpy[3]), rl));
      rix = pxi; riy = pyi;  // saved for the augment store
    }

    int jfin;
    int guard = N + 2;  // fail-fast bound (path length <= N+1); off-chain scalar
    while (true) {
      // ---- scan ALL my columns, maskless: marked have sv=-inf -> m=+inf
      double m[4];
#pragma unroll
      for (int k = 0; k < 4; ++k) {
        float dx = pxi - tx[k];
        float dy = pyi - ty[k];
        float c = FAST_SQRT(dx * dx + dy * dy);
        m[k] = ((double)c - ui0) - sv[k];  // reference rounding order (free cols)
      }
      double bm = fmin(fmin(m[0], m[1]), fmin(m[2], m[3]));

      // ---- wave value-min: 4 DPP butterfly stages + 2 all-lane swap stages
      DPP_MIN_STAGE(0xB1, 0xF);   // quad_perm [1,0,3,2]  (xor 1)
      DPP_MIN_STAGE(0x4E, 0xF);   // quad_perm [2,3,0,1]  (xor 2)
      DPP_MIN_STAGE(0x141, 0xF);  // row_half_mirror      (xor 4)
      DPP_MIN_STAGE(0x140, 0xF);  // row_mirror           (xor 8)
#if HAVE_PL_SWAP
      {  // xor 16 for ALL lanes: min over the unordered swapped pair
        int mlo = dlo(bm), mhi = dhi(bm);
        auto rlo = __builtin_amdgcn_permlane16_swap(mlo, mlo, false, false);
        auto rhi = __builtin_amdgcn_permlane16_swap(mhi, mhi, false, false);
        bm = fmin(mkd(rlo[0], rhi[0]), mkd(rlo[1], rhi[1]));
      }
      {  // xor 32 for ALL lanes
        int mlo = dlo(bm), mhi = dhi(bm);
        auto rlo = __builtin_amdgcn_permlane32_swap(mlo, mlo, false, false);
        auto rhi = __builtin_amdgcn_permlane32_swap(mhi, mhi, false, false);
        bm = fmin(mkd(rlo[0], rhi[0]), mkd(rlo[1], rhi[1]));
      }
      const double delta = bm;  // global min in EVERY lane (VGPR); no readlane
#else
      DPP_MIN_STAGE(0x142, 0xA);  // row_bcast15 -> rows 1,3
      DPP_MIN_STAGE(0x143, 0xC);  // row_bcast31 -> rows 2,3
      const double delta = mkd(__builtin_amdgcn_readlane(dlo(bm), 63),
                               __builtin_amdgcn_readlane(dhi(bm), 63));
#endif

      // ---- argmin j (first-index): k-major ballots == ascending j
      const unsigned long long b0 = __ballot(m[0] == delta);
      const unsigned long long b1 = __ballot(m[1] == delta);
      const unsigned long long b2 = __ballot(m[2] == delta);
      const unsigned long long b3 = __ballot(m[3] == delta);
      const int ks = b0 ? 0 : (b1 ? 1 : (b2 ? 2 : 3));
      const unsigned long long bb = b0 ? b0 : (b1 ? b1 : (b2 ? b2 : b3));
      const int ls = (__ffsll(bb) - 1) & 63;  // defined even if bb==0 (guarded)
      const int j1 = 1 + ls + 64 * ks;

      // ---- issue the ONLY per-step LDS op; no consumer until next scan
      const UC hop = ucofc[j1];

      // ---- dual update (exact sequential rounding; marked columns only)
      uv0 += delta;  // u[i] via virtual column 0 (marked from step 1)
#pragma unroll
      for (int k = 0; k < 4; ++k) {
        const unsigned long long ml = k == 0 ? ml0 : k == 1 ? ml1 : k == 2 ? ml2 : ml3;
        const double add = ((ml >> lane) & 1) ? delta : 0.0;
        v[k] -= add;
        uacc[k] += add;  // invariant: tracks u of my column's row while marked
      }

      // ---- loop exit: scalar bit test on assigned-masks (+ fail-fast guard)
      const unsigned long long am = ks == 0 ? am0 : ks == 1 ? am1 : ks == 2 ? am2 : am3;
      if (!((am >> ls) & 1) || --guard == 0) { jfin = j1; break; }

      // ---- mark j1: scalar mask bit + branchless owner-lane sv = -inf
      {
        const unsigned long long bit = 1ull << ls;
        if (ks == 0) ml0 |= bit; else if (ks == 1) ml1 |= bit;
        else if (ks == 2) ml2 |= bit; else ml3 |= bit;
      }
      const bool hit = (lane == ls);
#pragma unroll
      for (int k = 0; k < 4; ++k) {
        const bool selk = hit && (ks == k);
        sv[k] = selk ? NINF : sv[k];  // cndmask; uacc needs no seed (invariant)
      }
      // ---- hop to j1's row (waitcnt sinks to next scan's first use)
      ui0 = hop.u;
      pxi = hop.cx; pyi = hop.cy;
    }

    // ---- augment: record assignment + set uacc invariant for jfin's owner
    {
      const int fl = (jfin - 1) & 63, fs = ((jfin - 1) >> 6) & 3;
      const unsigned long long bit = 1ull << fl;
      if (fs == 0) am0 |= bit; else if (fs == 1) am1 |= bit;
      else if (fs == 2) am2 |= bit; else am3 |= bit;
      const bool ahit = (lane == fl);
#pragma unroll
      for (int k = 0; k < 4; ++k) {
        const bool selk = ahit && (fs == k);
        uacc[k] = selk ? uv0 : uacc[k];  // cndmask of wave-uniform value
      }
    }
    UC nu; nu.u = uv0; nu.cx = rix; nu.cy = riy;
    ucofc[jfin] = nu;  // wave-uniform b128 store (coords for future hops/MSE)
    // ---- flush invariant: unconditional owner-partitioned b64 stores
#pragma unroll
    for (int k = 0; k < 4; ++k) ucofc[1 + lane + 64 * k].u = uacc[k];
    // ---- restore scan duals (all columns unmarked again)
#pragma unroll
    for (int k = 0; k < 4; ++k) sv[k] = v[k];
    __builtin_amdgcn_wave_barrier();  // row-end ordering point (free)
  }

  __syncthreads();
  // ---- partial MSE: column j's matched row coords are in ucofc[j]
  double s = 0.0;
#pragma unroll
  for (int k = 0; k < 4; ++k) {
    int j = 1 + lane + 64 * k;
    UC t = ucofc[j];
    double dx = (double)t.cx - (double)tx[k];
    double dy = (double)t.cy - (double)ty[k];
    s += dx * dx + dy * dy;
  }
#pragma unroll
  for (int off = 1; off < 64; off <<= 1) s += __shfl_xor(s, off);
  if (lane == 0) partial[b] = s;
}

__global__ __launch_bounds__(64) void reduce_kernel(const double* __restrict__ partial,
                                                    float* __restrict__ out, int B) {
  double s = 0.0;
  for (int i = threadIdx.x; i < B; i += 64) s += partial[i];
#pragma unroll
  for (int off = 1; off < 64; off <<= 1) s += __shfl_xor(s, off);
  if (threadIdx.x == 0) out[0] = (float)(s / (double)(B * N * 2));
}

extern "C" void kernel_launch(void* const* d_in, const int* in_sizes, int n_in,
                              void* d_out, int out_size, void* d_ws, size_t ws_size,
                              hipStream_t stream) {
  const float* pred = (const float*)d_in[0];
  const float* target = (const float*)d_in[1];
  float* out = (float*)d_out;
  double* partial = (double*)d_ws;

  const int B = in_sizes[0] / (N * 2);  // 32

  hipLaunchKernelGGL(hung_kernel, dim3(B), dim3(64), 0, stream, pred, target, partial);
  hipLaunchKernelGGL(reduce_kernel, dim3(1), dim3(64), 0, stream, partial, out, B);
}

// Round 16
// 660.378 us; speedup vs baseline: 1.7951x; 1.1650x over previous
//
#include <hip/hip_runtime.h>
#include <math.h>

// Hungarian (reference-exact degenerate JV) + MSE.
// Anchored on r15 (bit-exact, 769us). Changes vs r15 (value-preserving):
//   * dual-update predicate: (ml>>lane)&1 -> (sv[k] == -inf). Equivalent:
//     NINF is installed exactly at mark and removed exactly at row-end
//     restore; v/coords are always finite. 2 ops/column instead of 4-5.
//   * ml0..3 mark masks DELETED (no remaining readers).
//   * v/sv/uacc + scan arithmetic as ext_vector_type(2) doubles -> clang can
//     emit v_pk_add_f64 (gfx90a+). Per-component IEEE identical; falls back
//     to the same scalar ops if not selected.
// Everything else byte-identical to r15 (DPP value-min + permlane-swap tail
// with fallback, delta==gmin, k-major ballots, am SGPR masks, uacc invariant,
// one ds_read_b128 per step, fail-fast guard, raw v_sqrt_f32).
// HARD RULE (r2/r3/r9): cross-lane mutable state crosses lanes ONLY via LDS
// live reads; readlane only for read-only data or same-step temporaries.

#define N 256

typedef double dbl2 __attribute__((ext_vector_type(2)));

static __device__ __forceinline__ int f2i(float x) { union { float f; int i; } u; u.f = x; return u.i; }
static __device__ __forceinline__ float i2f(int x) { union { float f; int i; } u; u.i = x; return u.f; }
static __device__ __forceinline__ double mkd(int lo, int hi) {
  union { unsigned long long u; double d; } w;
  w.u = (((unsigned long long)(unsigned)hi) << 32) | (unsigned)lo;
  return w.d;
}
static __device__ __forceinline__ int dlo(double d) { union { double d; unsigned long long u; } w; w.d = d; return (int)(unsigned)w.u; }
static __device__ __forceinline__ int dhi(double d) { union { double d; unsigned long long u; } w; w.d = d; return (int)(unsigned)(w.u >> 32); }

#if __has_builtin(__builtin_amdgcn_sqrtf)
#define FAST_SQRT(x) __builtin_amdgcn_sqrtf(x)
#else
#define FAST_SQRT(x) sqrtf(x)
#endif

#if __has_builtin(__builtin_amdgcn_permlane16_swap) && __has_builtin(__builtin_amdgcn_permlane32_swap)
#define HAVE_PL_SWAP 1
#else
#define HAVE_PL_SWAP 0
#endif

// One DPP f64-min stage with LITERAL ctrl/row_mask. Masked-out lanes keep
// their own bm (old operand). fmin == strict-< select for NaN-free values.
#define DPP_MIN_STAGE(CTRL, RMASK)                                              \
  {                                                                             \
    int mlo = dlo(bm), mhi = dhi(bm);                                           \
    int slo = __builtin_amdgcn_update_dpp(mlo, mlo, CTRL, RMASK, 0xF, false);   \
    int shi = __builtin_amdgcn_update_dpp(mhi, mhi, CTRL, RMASK, 0xF, false);   \
    bm = fmin(bm, mkd(slo, shi));                                               \
  }

struct alignas(16) UC { double u; float cx, cy; };  // one ds_read_b128

__global__ __launch_bounds__(64) void hung_kernel(const float* __restrict__ pred,
                                                  const float* __restrict__ target,
                                                  double* __restrict__ partial) {
  const int b = blockIdx.x;
  const int lane = threadIdx.x;  // single wave per block

  __shared__ UC ucofc[N + 1];  // per column: {u of its row, row pred coords}

  // Read-only per-lane data: columns j-1 = lane+64k; rows r-1 = lane+64k.
  float tx[4], ty[4], rpx[4], rpy[4];
  dbl2 v01 = {0.0, 0.0}, v23 = {0.0, 0.0};        // true column duals
  dbl2 sv01 = {0.0, 0.0}, sv23 = {0.0, 0.0};      // scan duals (-inf = marked)
  dbl2 ua01 = {0.0, 0.0}, ua23 = {0.0, 0.0};      // uacc invariant

  const float2* pv = (const float2*)pred + (size_t)b * N;
  const float2* tv = (const float2*)target + (size_t)b * N;
#pragma unroll
  for (int k = 0; k < 4; ++k) {
    int idx = lane + 64 * k;
    float2 pp = pv[idx];
    rpx[k] = pp.x; rpy[k] = pp.y;
    float2 tt = tv[idx];
    tx[k] = tt.x; ty[k] = tt.y;
  }
#pragma unroll
  for (int k = 0; k < 5; ++k) {
    int j = lane + 64 * k;
    if (j < N + 1) { UC z; z.u = 0.0; z.cx = 0.f; z.cy = 0.f; ucofc[j] = z; }
  }
  __syncthreads();

  // wave-uniform assigned-column masks (bit 'lane' of am_k <=> col 1+lane+64k)
  unsigned long long am0 = 0, am1 = 0, am2 = 0, am3 = 0;
  const double NINF = -__builtin_huge_val();

  for (int i = 1; i <= N; ++i) {
    double uv0 = 0.0;  // live u[i] (virtual column 0), wave-uniform
    double ui0 = 0.0;  // row-start u of current i0; row i itself starts at 0
    float pxi, pyi, rix, riy;
    {
      const int rl = (i - 1) & 63, rs = (i - 1) >> 6;
      pxi = i2f(__builtin_amdgcn_readlane(
          rs == 0 ? f2i(rpx[0]) : rs == 1 ? f2i(rpx[1]) : rs == 2 ? f2i(rpx[2]) : f2i(rpx[3]), rl));
      pyi = i2f(__builtin_amdgcn_readlane(
          rs == 0 ? f2i(rpy[0]) : rs == 1 ? f2i(rpy[1]) : rs == 2 ? f2i(rpy[2]) : f2i(rpy[3]), rl));
      rix = pxi; riy = pyi;  // saved for the augment store
    }

    int jfin;
    int guard = N + 2;  // fail-fast bound (path length <= N+1); off-chain scalar
    while (true) {
      // ---- scan ALL my columns, maskless: marked have sv=-inf -> m=+inf
      float dx0 = pxi - tx[0], dy0 = pyi - ty[0];
      float dx1 = pxi - tx[1], dy1 = pyi - ty[1];
      float dx2 = pxi - tx[2], dy2 = pyi - ty[2];
      float dx3 = pxi - tx[3], dy3 = pyi - ty[3];
      float c0 = FAST_SQRT(dx0 * dx0 + dy0 * dy0);
      float c1 = FAST_SQRT(dx1 * dx1 + dy1 * dy1);
      float c2 = FAST_SQRT(dx2 * dx2 + dy2 * dy2);
      float c3 = FAST_SQRT(dx3 * dx3 + dy3 * dy3);
      const dbl2 ui2 = {ui0, ui0};
      dbl2 c01 = {(double)c0, (double)c1};
      dbl2 c23 = {(double)c2, (double)c3};
      const dbl2 m01 = (c01 - ui2) - sv01;  // reference rounding order per comp
      const dbl2 m23 = (c23 - ui2) - sv23;
      double bm = fmin(fmin(m01.x, m01.y), fmin(m23.x, m23.y));

      // ---- wave value-min: 4 DPP butterfly stages + 2 all-lane swap stages
      DPP_MIN_STAGE(0xB1, 0xF);   // quad_perm [1,0,3,2]  (xor 1)
      DPP_MIN_STAGE(0x4E, 0xF);   // quad_perm [2,3,0,1]  (xor 2)
      DPP_MIN_STAGE(0x141, 0xF);  // row_half_mirror      (xor 4)
      DPP_MIN_STAGE(0x140, 0xF);  // row_mirror           (xor 8)
#if HAVE_PL_SWAP
      {  // xor 16 for ALL lanes: min over the unordered swapped pair
        int mlo = dlo(bm), mhi = dhi(bm);
        auto rlo = __builtin_amdgcn_permlane16_swap(mlo, mlo, false, false);
        auto rhi = __builtin_amdgcn_permlane16_swap(mhi, mhi, false, false);
        bm = fmin(mkd(rlo[0], rhi[0]), mkd(rlo[1], rhi[1]));
      }
      {  // xor 32 for ALL lanes
        int mlo = dlo(bm), mhi = dhi(bm);
        auto rlo = __builtin_amdgcn_permlane32_swap(mlo, mlo, false, false);
        auto rhi = __builtin_amdgcn_permlane32_swap(mhi, mhi, false, false);
        bm = fmin(mkd(rlo[0], rhi[0]), mkd(rlo[1], rhi[1]));
      }
      const double delta = bm;  // global min in EVERY lane (VGPR); no readlane
#else
      DPP_MIN_STAGE(0x142, 0xA);  // row_bcast15 -> rows 1,3
      DPP_MIN_STAGE(0x143, 0xC);  // row_bcast31 -> rows 2,3
      const double delta = mkd(__builtin_amdgcn_readlane(dlo(bm), 63),
                               __builtin_amdgcn_readlane(dhi(bm), 63));
#endif

      // ---- argmin j (first-index): k-major ballots == ascending j
      const unsigned long long b0 = __ballot(m01.x == delta);
      const unsigned long long b1 = __ballot(m01.y == delta);
      const unsigned long long b2 = __ballot(m23.x == delta);
      const unsigned long long b3 = __ballot(m23.y == delta);
      const int ks = b0 ? 0 : (b1 ? 1 : (b2 ? 2 : 3));
      const unsigned long long bb = b0 ? b0 : (b1 ? b1 : (b2 ? b2 : b3));
      const int ls = (__ffsll(bb) - 1) & 63;  // defined even if bb==0 (guarded)
      const int j1 = 1 + ls + 64 * ks;

      // ---- issue the ONLY per-step LDS op; no consumer until next scan
      const UC hop = ucofc[j1];

      // ---- dual update (exact sequential rounding; marked <=> sv == -inf)
      uv0 += delta;  // u[i] via virtual column 0 (marked from step 1)
      {
        const dbl2 a01 = {sv01.x == NINF ? delta : 0.0, sv01.y == NINF ? delta : 0.0};
        const dbl2 a23 = {sv23.x == NINF ? delta : 0.0, sv23.y == NINF ? delta : 0.0};
        v01 -= a01; ua01 += a01;   // v_pk_add_f64 candidates
        v23 -= a23; ua23 += a23;
      }

      // ---- loop exit: scalar bit test on assigned-masks (+ fail-fast guard)
      const unsigned long long am = ks == 0 ? am0 : ks == 1 ? am1 : ks == 2 ? am2 : am3;
      if (!((am >> ls) & 1) || --guard == 0) { jfin = j1; break; }

      // ---- mark j1: branchless owner-lane sv = -inf
      const bool hit = (lane == ls);
      sv01.x = (hit && ks == 0) ? NINF : sv01.x;
      sv01.y = (hit && ks == 1) ? NINF : sv01.y;
      sv23.x = (hit && ks == 2) ? NINF : sv23.x;
      sv23.y = (hit && ks == 3) ? NINF : sv23.y;
      // ---- hop to j1's row (waitcnt sinks to next scan's first use)
      ui0 = hop.u;
      pxi = hop.cx; pyi = hop.cy;
    }

    // ---- augment: record assignment + set uacc invariant for jfin's owner
    {
      const int fl = (jfin - 1) & 63, fs = ((jfin - 1) >> 6) & 3;
      const unsigned long long bit = 1ull << fl;
      if (fs == 0) am0 |= bit; else if (fs == 1) am1 |= bit;
      else if (fs == 2) am2 |= bit; else am3 |= bit;
      const bool ahit = (lane == fl);
      ua01.x = (ahit && fs == 0) ? uv0 : ua01.x;
      ua01.y = (ahit && fs == 1) ? uv0 : ua01.y;
      ua23.x = (ahit && fs == 2) ? uv0 : ua23.x;
      ua23.y = (ahit && fs == 3) ? uv0 : ua23.y;
    }
    UC nu; nu.u = uv0; nu.cx = rix; nu.cy = riy;
    ucofc[jfin] = nu;  // wave-uniform b128 store (coords for future hops/MSE)
    // ---- flush invariant: unconditional owner-partitioned b64 stores
    ucofc[1 + lane].u       = ua01.x;
    ucofc[1 + lane + 64].u  = ua01.y;
    ucofc[1 + lane + 128].u = ua23.x;
    ucofc[1 + lane + 192].u = ua23.y;
    // ---- restore scan duals (all columns unmarked again)
    sv01 = v01; sv23 = v23;
    __builtin_amdgcn_wave_barrier();  // row-end ordering point (free)
  }

  __syncthreads();
  // ---- partial MSE: column j's matched row coords are in ucofc[j]
  double s = 0.0;
#pragma unroll
  for (int k = 0; k < 4; ++k) {
    int j = 1 + lane + 64 * k;
    UC t = ucofc[j];
    double dx = (double)t.cx - (double)tx[k];
    double dy = (double)t.cy - (double)ty[k];
    s += dx * dx + dy * dy;
  }
#pragma unroll
  for (int off = 1; off < 64; off <<= 1) s += __shfl_xor(s, off);
  if (lane == 0) partial[b] = s;
}

__global__ __launch_bounds__(64) void reduce_kernel(const double* __restrict__ partial,
                                                    float* __restrict__ out, int B) {
  double s = 0.0;
  for (int i = threadIdx.x; i < B; i += 64) s += partial[i];
#pragma unroll
  for (int off = 1; off < 64; off <<= 1) s += __shfl_xor(s, off);
  if (threadIdx.x == 0) out[0] = (float)(s / (double)(B * N * 2));
}

extern "C" void kernel_launch(void* const* d_in, const int* in_sizes, int n_in,
                              void* d_out, int out_size, void* d_ws, size_t ws_size,
                              hipStream_t stream) {
  const float* pred = (const float*)d_in[0];
  const float* target = (const float*)d_in[1];
  float* out = (float*)d_out;
  double* partial = (double*)d_ws;

  const int B = in_sizes[0] / (N * 2);  // 32

  hipLaunchKernelGGL(hung_kernel, dim3(B), dim3(64), 0, stream, pred, target, partial);
  hipLaunchKernelGGL(reduce_kernel, dim3(1), dim3(64), 0, stream, partial, out, B);
}

// Round 17
// 649.437 us; speedup vs baseline: 1.8254x; 1.0168x over previous
//
#include <hip/hip_runtime.h>
#include <math.h>

// Hungarian (reference-exact degenerate JV) + MSE.
// Anchored on r16 (bit-exact, 660us). Changes vs r16 (value-preserving):
//   * LANE-MAJOR column ownership: lane owns j-1 in {4L..4L+3}. Ascending j
//     == (lane,k) lex -> first-index argmin = ONE ballot(bml==delta) + ffs +
//     readlane(bk,ls) where bk = first k with m[k]==bml, computed OFF-CHAIN
//     during the DPP stages. (Was: 4 f64-cmp ballots + cselect chain.)
//     readlane of same-step temporaries = r7/r8-proven class.
//   * SoA LDS: u_lds[256] (f64) + c_lds[256] (float2), 0-based j. Hop = two
//     PARALLEL uniform reads (b64+b64). Row-end flush = two aligned
//     contiguous ds_write_b128 (lane's 4 doubles are 32B-contiguous).
//   * target coords + final MSE reads vectorized as float4.
// Everything else: r16 structure (DPP value-min + permlane-swap tail,
// delta==gmin, sv==-inf marked-predicate, pk f64 updates, am SGPR masks,
// uacc invariant + row-end flush, fail-fast guard, raw v_sqrt_f32).
// HARD RULE (r2/r3/r9): cross-lane mutable PERSISTENT state moves ONLY via
// LDS live reads; readlane only for read-only data or same-step temporaries.

#define N 256

typedef double dbl2 __attribute__((ext_vector_type(2)));

static __device__ __forceinline__ int f2i(float x) { union { float f; int i; } u; u.f = x; return u.i; }
static __device__ __forceinline__ float i2f(int x) { union { float f; int i; } u; u.i = x; return u.f; }
static __device__ __forceinline__ double mkd(int lo, int hi) {
  union { unsigned long long u; double d; } w;
  w.u = (((unsigned long long)(unsigned)hi) << 32) | (unsigned)lo;
  return w.d;
}
static __device__ __forceinline__ int dlo(double d) { union { double d; unsigned long long u; } w; w.d = d; return (int)(unsigned)w.u; }
static __device__ __forceinline__ int dhi(double d) { union { double d; unsigned long long u; } w; w.d = d; return (int)(unsigned)(w.u >> 32); }

#if __has_builtin(__builtin_amdgcn_sqrtf)
#define FAST_SQRT(x) __builtin_amdgcn_sqrtf(x)
#else
#define FAST_SQRT(x) sqrtf(x)
#endif

#if __has_builtin(__builtin_amdgcn_permlane16_swap) && __has_builtin(__builtin_amdgcn_permlane32_swap)
#define HAVE_PL_SWAP 1
#else
#define HAVE_PL_SWAP 0
#endif

#define DPP_MIN_STAGE(CTRL, RMASK)                                              \
  {                                                                             \
    int mlo = dlo(bm), mhi = dhi(bm);                                           \
    int slo = __builtin_amdgcn_update_dpp(mlo, mlo, CTRL, RMASK, 0xF, false);   \
    int shi = __builtin_amdgcn_update_dpp(mhi, mhi, CTRL, RMASK, 0xF, false);   \
    bm = fmin(bm, mkd(slo, shi));                                               \
  }

__global__ __launch_bounds__(64) void hung_kernel(const float* __restrict__ pred,
                                                  const float* __restrict__ target,
                                                  double* __restrict__ partial) {
  const int b = blockIdx.x;
  const int lane = threadIdx.x;  // single wave per block

  __shared__ double u_lds[N];   // u of the row assigned to column (0-based j)
  __shared__ float2 c_lds[N];   // pred coords of that row

  // Column data LANE-MAJOR: lane owns cols 4*lane+k (0-based), k=0..3.
  // Row data k-major as before: row r-1 = lane + 64k (read-only, readlane).
  float tx[4], ty[4], rpx[4], rpy[4];
  dbl2 v01 = {0.0, 0.0}, v23 = {0.0, 0.0};        // true column duals
  dbl2 sv01 = {0.0, 0.0}, sv23 = {0.0, 0.0};      // scan duals (-inf = marked)
  dbl2 ua01 = {0.0, 0.0}, ua23 = {0.0, 0.0};      // uacc invariant

  const float2* pv = (const float2*)pred + (size_t)b * N;
  const float2* tv = (const float2*)target + (size_t)b * N;
  {  // target coords: two float4 loads (4 consecutive float2s per lane)
    float4 t01 = ((const float4*)tv)[2 * lane];
    float4 t23 = ((const float4*)tv)[2 * lane + 1];
    tx[0] = t01.x; ty[0] = t01.y; tx[1] = t01.z; ty[1] = t01.w;
    tx[2] = t23.x; ty[2] = t23.y; tx[3] = t23.z; ty[3] = t23.w;
  }
#pragma unroll
  for (int k = 0; k < 4; ++k) {  // pred rows, k-major (coalesced float2)
    float2 pp = pv[lane + 64 * k];
    rpx[k] = pp.x; rpy[k] = pp.y;
  }
#pragma unroll
  for (int k = 0; k < 4; ++k) {
    int j = lane + 64 * k;
    u_lds[j] = 0.0; c_lds[j] = make_float2(0.f, 0.f);
  }
  __syncthreads();

  // wave-uniform assigned masks: bit 'fl' of am_k <=> col 4*fl+k assigned
  unsigned long long am0 = 0, am1 = 0, am2 = 0, am3 = 0;
  const double NINF = -__builtin_huge_val();

  for (int i = 1; i <= N; ++i) {
    double uv0 = 0.0;  // live u[i] (virtual column 0), wave-uniform
    double ui0 = 0.0;  // row-start u of current i0; row i itself starts at 0
    float pxi, pyi, rix, riy;
    {
      const int rl = (i - 1) & 63, rs = (i - 1) >> 6;
      pxi = i2f(__builtin_amdgcn_readlane(
          rs == 0 ? f2i(rpx[0]) : rs == 1 ? f2i(rpx[1]) : rs == 2 ? f2i(rpx[2]) : f2i(rpx[3]), rl));
      pyi = i2f(__builtin_amdgcn_readlane(
          rs == 0 ? f2i(rpy[0]) : rs == 1 ? f2i(rpy[1]) : rs == 2 ? f2i(rpy[2]) : f2i(rpy[3]), rl));
      rix = pxi; riy = pyi;  // saved for the augment store
    }

    int jfin0;
    int guard = N + 2;  // fail-fast bound; off-chain scalar
    while (true) {
      // ---- scan my 4 columns, maskless: marked have sv=-inf -> m=+inf
      float dx0 = pxi - tx[0], dy0 = pyi - ty[0];
      float dx1 = pxi - tx[1], dy1 = pyi - ty[1];
      float dx2 = pxi - tx[2], dy2 = pyi - ty[2];
      float dx3 = pxi - tx[3], dy3 = pyi - ty[3];
      float c0 = FAST_SQRT(dx0 * dx0 + dy0 * dy0);
      float c1 = FAST_SQRT(dx1 * dx1 + dy1 * dy1);
      float c2 = FAST_SQRT(dx2 * dx2 + dy2 * dy2);
      float c3 = FAST_SQRT(dx3 * dx3 + dy3 * dy3);
      const dbl2 ui2 = {ui0, ui0};
      dbl2 c01 = {(double)c0, (double)c1};
      dbl2 c23 = {(double)c2, (double)c3};
      const dbl2 m01 = (c01 - ui2) - sv01;  // reference rounding order
      const dbl2 m23 = (c23 - ui2) - sv23;
      const double bml = fmin(fmin(m01.x, m01.y), fmin(m23.x, m23.y));

      // bk = first k with m[k]==bml (off-chain; overlaps the DPP stages)
      const int bk = (m01.x == bml) ? 0 : (m01.y == bml) ? 1 : (m23.x == bml) ? 2 : 3;

      // ---- wave value-min: 4 DPP butterfly stages + 2 all-lane swap stages
      double bm = bml;
      DPP_MIN_STAGE(0xB1, 0xF);   // quad_perm [1,0,3,2]  (xor 1)
      DPP_MIN_STAGE(0x4E, 0xF);   // quad_perm [2,3,0,1]  (xor 2)
      DPP_MIN_STAGE(0x141, 0xF);  // row_half_mirror      (xor 4)
      DPP_MIN_STAGE(0x140, 0xF);  // row_mirror           (xor 8)
#if HAVE_PL_SWAP
      {
        int mlo = dlo(bm), mhi = dhi(bm);
        auto rlo = __builtin_amdgcn_permlane16_swap(mlo, mlo, false, false);
        auto rhi = __builtin_amdgcn_permlane16_swap(mhi, mhi, false, false);
        bm = fmin(mkd(rlo[0], rhi[0]), mkd(rlo[1], rhi[1]));
      }
      {
        int mlo = dlo(bm), mhi = dhi(bm);
        auto rlo = __builtin_amdgcn_permlane32_swap(mlo, mlo, false, false);
        auto rhi = __builtin_amdgcn_permlane32_swap(mhi, mhi, false, false);
        bm = fmin(mkd(rlo[0], rhi[0]), mkd(rlo[1], rhi[1]));
      }
      const double delta = bm;  // global min in EVERY lane
#else
      DPP_MIN_STAGE(0x142, 0xA);
      DPP_MIN_STAGE(0x143, 0xC);
      const double delta = mkd(__builtin_amdgcn_readlane(dlo(bm), 63),
                               __builtin_amdgcn_readlane(dhi(bm), 63));
#endif

      // ---- first-index argmin, lane-major: ONE ballot + ffs + readlane(bk)
      const unsigned long long L = __ballot(bml == delta);
      const int ls = (__ffsll(L) - 1) & 63;
      const int bks = __builtin_amdgcn_readlane(bk, ls) & 3;  // same-step temp
      const int j1i = 4 * ls + bks;  // 0-based column

      // ---- hop reads: two PARALLEL uniform LDS loads; consumed next scan
      const double uj = u_lds[j1i];
      const float2 cj = c_lds[j1i];

      // ---- dual update (exact sequential rounding; marked <=> sv == -inf)
      uv0 += delta;
      {
        const dbl2 a01 = {sv01.x == NINF ? delta : 0.0, sv01.y == NINF ? delta : 0.0};
        const dbl2 a23 = {sv23.x == NINF ? delta : 0.0, sv23.y == NINF ? delta : 0.0};
        v01 -= a01; ua01 += a01;
        v23 -= a23; ua23 += a23;
      }

      // ---- loop exit: scalar bit test on assigned-masks (+ guard)
      const unsigned long long am = bks == 0 ? am0 : bks == 1 ? am1 : bks == 2 ? am2 : am3;
      if (!((am >> ls) & 1) || --guard == 0) { jfin0 = j1i; break; }

      // ---- mark j1: branchless owner-lane sv = -inf
      const bool hit = (lane == ls);
      sv01.x = (hit && bks == 0) ? NINF : sv01.x;
      sv01.y = (hit && bks == 1) ? NINF : sv01.y;
      sv23.x = (hit && bks == 2) ? NINF : sv23.x;
      sv23.y = (hit && bks == 3) ? NINF : sv23.y;
      // ---- hop to j1's row
      ui0 = uj;
      pxi = cj.x; pyi = cj.y;
    }

    // ---- augment: masks + uacc invariant for jfin's owner, coords store
    {
      const int fl = (jfin0 >> 2) & 63, fs = jfin0 & 3;
      const unsigned long long bit = 1ull << fl;
      if (fs == 0) am0 |= bit; else if (fs == 1) am1 |= bit;
      else if (fs == 2) am2 |= bit; else am3 |= bit;
      const bool ahit = (lane == fl);
      ua01.x = (ahit && fs == 0) ? uv0 : ua01.x;
      ua01.y = (ahit && fs == 1) ? uv0 : ua01.y;
      ua23.x = (ahit && fs == 2) ? uv0 : ua23.x;
      ua23.y = (ahit && fs == 3) ? uv0 : ua23.y;
    }
    c_lds[jfin0] = make_float2(rix, riy);  // wave-uniform store
    // ---- flush invariant: two aligned contiguous ds_write_b128 per lane
    // (covers jfin0's u too: its owner's ua was just set to uv0)
    *(dbl2*)&u_lds[4 * lane] = ua01;
    *(dbl2*)&u_lds[4 * lane + 2] = ua23;
    // ---- restore scan duals
    sv01 = v01; sv23 = v23;
    __builtin_amdgcn_wave_barrier();  // row-end ordering point (free)
  }

  __syncthreads();
  // ---- partial MSE: my columns 4*lane+k; matched-row coords in c_lds
  double s = 0.0;
  {
    float4 cc01 = *(const float4*)&c_lds[4 * lane];
    float4 cc23 = *(const float4*)&c_lds[4 * lane + 2];
    double dx, dy;
    dx = (double)cc01.x - (double)tx[0]; dy = (double)cc01.y - (double)ty[0]; s += dx * dx + dy * dy;
    dx = (double)cc01.z - (double)tx[1]; dy = (double)cc01.w - (double)ty[1]; s += dx * dx + dy * dy;
    dx = (double)cc23.x - (double)tx[2]; dy = (double)cc23.y - (double)ty[2]; s += dx * dx + dy * dy;
    dx = (double)cc23.z - (double)tx[3]; dy = (double)cc23.w - (double)ty[3]; s += dx * dx + dy * dy;
  }
#pragma unroll
  for (int off = 1; off < 64; off <<= 1) s += __shfl_xor(s, off);
  if (lane == 0) partial[b] = s;
}

__global__ __launch_bounds__(64) void reduce_kernel(const double* __restrict__ partial,
                                                    float* __restrict__ out, int B) {
  double s = 0.0;
  for (int i = threadIdx.x; i < B; i += 64) s += partial[i];
#pragma unroll
  for (int off = 1; off < 64; off <<= 1) s += __shfl_xor(s, off);
  if (threadIdx.x == 0) out[0] = (float)(s / (double)(B * N * 2));
}

extern "C" void kernel_launch(void* const* d_in, const int* in_sizes, int n_in,
                              void* d_out, int out_size, void* d_ws, size_t ws_size,
                              hipStream_t stream) {
  const float* pred = (const float*)d_in[0];
  const float* target = (const float*)d_in[1];
  float* out = (float*)d_out;
  double* partial = (double*)d_ws;

  const int B = in_sizes[0] / (N * 2);  // 32

  hipLaunchKernelGGL(hung_kernel, dim3(B), dim3(64), 0, stream, pred, target, partial);
  hipLaunchKernelGGL(reduce_kernel, dim3(1), dim3(64), 0, stream, partial, out, B);
}